// Round 9
// baseline (109.915 us; speedup 1.0000x reference)
//
#include <hip/hip_runtime.h>
#include <math.h>

// Problem constants (fixed by setup_inputs)
constexpr int NB = 2;     // batch
constexpr int NC = 2;     // channels
constexpr int NT = 500;   // time
constexpr int NF = 129;   // freq
constexpr int NH = 16;    // heads
constexpr int ND = 100;   // delay

// Rank-3 factorization: V_h = sum_{i,j in {0,1,2}} WM'(h,i) WR'(h,j) C_ij,
// index 2 = ones-channel (bias). Only i,j<2 need MFMA maps:
//   C_ij[t,d] = sum_f Xm_i[t,f] Xr_j[u,f],  u = t+d-99  (0 when u<0)
// Degenerate maps reconstructed in csy:
//   C_i2 = rsm_i[t]*[u>=0], C_2j = rsr_j[u]*[u>=0], C_22 = NF*[u>=0]
constexpr size_t CSTRIDE = (size_t)NT * ND;              // 50,000 floats/map
constexpr size_t C4ELEMS = (size_t)NB * 4 * CSTRIDE;     // 1.6 MB
constexpr int RSRLEN = 600;                              // rsr_ext: index u+99, 99 leading zeros

typedef _Float16 f16;
typedef _Float16 f16x4 __attribute__((ext_vector_type(4)));
typedef float    f32x4 __attribute__((ext_vector_type(4)));

// ------------------- Kernel 1: 4 MFMA maps + exact rowsums -------------------
// Block = (b, j in {0,1}, t-tile). Stage ref_j band (128 u rows) + mic0/mic1
// (2x16 t rows) as f16. MFMA -> C_{0j}, C_{1j}. Plus f32 rowsums via shuffles.
constexpr int TT    = 16;
constexpr int NTT   = 32;
constexpr int BROWS = 128;                 // ref band rows
constexpr int LROWS = 160;                 // + 2*16 mic rows
constexpr int LSTR  = 148;

__global__ __launch_bounds__(256) void corr_kernel(
    const float* __restrict__ x_mic, const float* __restrict__ x_ref,
    float* __restrict__ C, float* __restrict__ rsm, float* __restrict__ rsr)
{
    __shared__ f16 Lds[LROWS * LSTR];   // 47,360 B

    const int tid = threadIdx.x;
    const int tt = blockIdx.x & 31;
    const int bj = blockIdx.x >> 5;     // b*2 + j
    const int j = bj & 1, b = bj >> 1;
    const int ts = tt * TT;
    const int US = ts - (ND - 1);       // global u of LDS row 0

    const float* xr = x_ref + (size_t)b * NC * NT * NF;
    const float* xm = x_mic + (size_t)b * NC * NT * NF;

    const int w = tid >> 6;   // wave 0..3
    const int l = tid & 63;

    // ---- stage 160 rows; lane-per-column, coalesced
    for (int rr = 0; rr < 40; ++rr) {
        const int r = w + 4 * rr;
        f16* row = Lds + r * LSTR;
        float v0 = 0.f, v1 = 0.f, v2 = 0.f;
        if (r < BROWS) {                       // ref channel j, row u
            const int u = US + r;
            if (u >= 0 && u < NT) {
                const float* p = xr + (size_t)j * NT * NF + (size_t)u * NF;
                v0 = p[l]; v1 = p[l + 64]; if (l == 0) v2 = p[128];
            }
        } else {                               // mic channel i, row t
            const int q = r - BROWS;
            const int i = q >> 4;
            const int t = ts + (q & 15);
            if (t < NT) {
                const float* p = xm + (size_t)i * NT * NF + (size_t)t * NF;
                v0 = p[l]; v1 = p[l + 64]; if (l == 0) v2 = p[128];
            }
        }
        row[l]      = (f16)v0;
        row[l + 64] = (f16)v1;
        if (l < LSTR - 128) row[128 + l] = (l == 0) ? (f16)v2 : (f16)0.f;
    }
    __syncthreads();

    // ---- MFMA: wave w covers u_loc in [32w, 32w+32); 2 mic maps x 2 subtiles
    const int lr = l & 15;
    const int lk = l >> 4;
    f32x4 acc[2][2] = {};

    #pragma unroll
    for (int kk = 0; kk < 9; ++kk) {
        const int fo = 16 * kk + 4 * lk;
        f16x4 bf0 = *(const f16x4*)&Lds[(32*w      + lr) * LSTR + fo];
        f16x4 bf1 = *(const f16x4*)&Lds[(32*w + 16 + lr) * LSTR + fo];
        #pragma unroll
        for (int i = 0; i < 2; ++i) {
            f16x4 af = *(const f16x4*)&Lds[(BROWS + 16*i + lr) * LSTR + fo];
            acc[i][0] = __builtin_amdgcn_mfma_f32_16x16x16f16(af, bf0, acc[i][0], 0, 0, 0);
            acc[i][1] = __builtin_amdgcn_mfma_f32_16x16x16f16(af, bf1, acc[i][1], 0, 0, 0);
        }
    }

    // ---- epilogue: D row = t_loc = 4*lk+jj, col = u_loc; d = u_loc - t_loc
    #pragma unroll
    for (int i = 0; i < 2; ++i) {
        float* Cb = C + ((size_t)b * 4 + i*2 + j) * CSTRIDE;
        #pragma unroll
        for (int n = 0; n < 2; ++n) {
            const int u_loc = 32*w + 16*n + lr;
            #pragma unroll
            for (int jj = 0; jj < 4; ++jj) {
                const int t_loc = 4*lk + jj;
                const int t_g = ts + t_loc;
                const int d = u_loc - t_loc;
                if (t_g < NT && d >= 0 && d < ND)
                    Cb[(size_t)t_g * ND + d] = acc[i][n][jj];
            }
        }
    }

    // ---- exact f32 rowsums (global reads + shuffle reduce; no LDS dep)
    // rsr_j[u] for u in [ts, ts+16): 4 rows per wave
    #pragma unroll
    for (int k = 0; k < 4; ++k) {
        const int u = ts + 4*w + k;
        if (u < NT) {
            const float* p = xr + (size_t)j * NT * NF + (size_t)u * NF;
            float v = p[l] + p[l + 64] + ((l == 0) ? p[128] : 0.f);
            #pragma unroll
            for (int o = 32; o > 0; o >>= 1) v += __shfl_down(v, o, 64);
            if (l == 0) rsr[((size_t)b*2 + j) * RSRLEN + 99 + u] = v;
        }
    }
    // rsm_i[t] (j==0 blocks only): 8 rows per wave
    if (j == 0) {
        #pragma unroll
        for (int k = 0; k < 8; ++k) {
            const int q = 8*w + k;           // 0..31
            const int i = q >> 4;
            const int t = ts + (q & 15);
            if (t < NT) {
                const float* p = xm + (size_t)i * NT * NF + (size_t)t * NF;
                float v = p[l] + p[l + 64] + ((l == 0) ? p[128] : 0.f);
                #pragma unroll
                for (int o = 32; o > 0; o >>= 1) v += __shfl_down(v, o, 64);
                if (l == 0) rsm[((size_t)b*2 + i) * NT + t] = v;
            }
        }
    }
    // zero the 99 leading (u<0) rsr_ext entries
    if (tt == 0 && tid < 99)
        rsr[((size_t)b*2 + j) * RSRLEN + tid] = 0.f;
}

// ---------------- Kernel 2: folded conv + softmax + y (fused) ----------------
// S[t,d] = b_conv + sum_{valid taps} { sum_{i,j<2} G[3i+j][tap]*C_ij[t',d']
//          + [u'>=0]*Bt[tap] + G[6][tap]*rsr0_ext[u'+99] + G[7][tap]*rsr1_ext[u'+99] }
// Bt[tap] = G[8][tap]*NF + G[2][tap]*rsm0[t'] + G[5][tap]*rsm1[t']
__global__ __launch_bounds__(256) void csy_kernel(
    const float* __restrict__ C, const float* __restrict__ rsm,
    const float* __restrict__ rsr, const float* __restrict__ w_conv,
    const float* __restrict__ b_conv,
    const float* __restrict__ w_mic, const float* __restrict__ b_mic,
    const float* __restrict__ w_ref, const float* __restrict__ b_ref,
    const float* __restrict__ x_ref, float* __restrict__ y)
{
    const int t = blockIdx.x % NT;
    const int b = blockIdx.x / NT;
    const int tid = threadIdx.x;

    __shared__ float G[9][15];
    __shared__ float Bt[15];
    __shared__ float Alds[ND];
    __shared__ float red[4];

    // folded conv weights G[m=3i+j][tap], index 2 = bias channel
    if (tid < 9 * 15) {
        const int m = tid / 15, tap = tid % 15;
        const int i = m / 3, jj = m % 3;
        float s = 0.f;
        for (int h = 0; h < NH; ++h) {
            const float a  = (i  < 2) ? w_mic[h*NC + i]  : b_mic[h];
            const float bb = (jj < 2) ? w_ref[h*NC + jj] : b_ref[h];
            s += w_conv[h*15 + tap] * a * bb;
        }
        G[m][tap] = s;
    }
    __syncthreads();

    if (tid < 15) {
        const int kt = tid / 3;
        const int tp = t - 4 + kt;
        float v = 0.f;
        if (tp >= 0)
            v = G[8][tid] * (float)NF
              + G[2][tid] * rsm[(size_t)(b*2 + 0) * NT + tp]
              + G[5][tid] * rsm[(size_t)(b*2 + 1) * NT + tp];
        Bt[tid] = v;
    }
    __syncthreads();

    const int d = tid;
    float s = 0.f;
    if (d < ND) {
        const float* Cb   = C + (size_t)b * 4 * CSTRIDE;
        const float* rsr0 = rsr + (size_t)b * 2 * RSRLEN;
        const float* rsr1 = rsr0 + RSRLEN;
        #pragma unroll
        for (int kt = 0; kt < 5; ++kt) {
            const int tp = t - 4 + kt;
            if (tp < 0) continue;               // block-uniform
            #pragma unroll
            for (int kd = 0; kd < 3; ++kd) {
                const int dp = d - 1 + kd;
                if (dp < 0 || dp >= ND) continue;
                const int tap = kt*3 + kd;
                const size_t off = (size_t)tp * ND + dp;
                float a2 = G[0][tap] * Cb[off]
                         + G[1][tap] * Cb[CSTRIDE   + off]
                         + G[3][tap] * Cb[2*CSTRIDE + off]
                         + G[4][tap] * Cb[3*CSTRIDE + off];
                const int ue = tp + dp;         // u' + 99, in [0, 598]
                a2 += G[6][tap] * rsr0[ue] + G[7][tap] * rsr1[ue];
                s += a2 + ((ue >= 99) ? Bt[tap] : 0.f);
            }
        }
        s += b_conv[0];
    }

    // softmax over d across waves 0..1
    if (tid < 128) {
        float mx = (d < ND) ? s : -3.4e38f;
        #pragma unroll
        for (int o = 32; o > 0; o >>= 1) mx = fmaxf(mx, __shfl_down(mx, o, 64));
        if ((tid & 63) == 0) red[tid >> 6] = mx;
    }
    __syncthreads();
    const float mx = fmaxf(red[0], red[1]);
    const float e = (d < ND) ? __expf(s - mx) : 0.f;
    if (tid < 128) {
        float sm = e;
        #pragma unroll
        for (int o = 32; o > 0; o >>= 1) sm += __shfl_down(sm, o, 64);
        if ((tid & 63) == 0) red[2 + (tid >> 6)] = sm;
    }
    __syncthreads();
    const float inv = 1.f / (red[2] + red[3]);
    if (d < ND) Alds[d] = e * inv;
    __syncthreads();

    // Phase B: y[b,c,t,f] = sum_d A[d] * x_ref[b,c,t+d-99,f]
    const int d0 = (t >= ND - 1) ? 0 : (ND - 1 - t);
    for (int o = tid; o < NC * NF; o += 256) {
        const int c = o / NF, f = o - c * NF;
        const float* X = x_ref + ((size_t)(b*NC + c) * NT + (t + d0 - (ND - 1))) * NF + f;
        float acc = 0.f;
        #pragma unroll 4
        for (int dd = d0; dd < ND; ++dd) {
            acc += Alds[dd] * X[0];
            X += NF;
        }
        y[((size_t)(b*NC + c) * NT + t) * NF + f] = acc;
    }
}

// ------------------------- launcher -------------------------
extern "C" void kernel_launch(void* const* d_in, const int* in_sizes, int n_in,
                              void* d_out, int out_size, void* d_ws, size_t ws_size,
                              hipStream_t stream)
{
    const float* x_mic  = (const float*)d_in[0];
    const float* x_ref  = (const float*)d_in[1];
    const float* w_mic  = (const float*)d_in[2];
    const float* b_mic  = (const float*)d_in[3];
    const float* w_ref  = (const float*)d_in[4];
    const float* b_ref  = (const float*)d_in[5];
    const float* w_conv = (const float*)d_in[6];
    const float* b_conv = (const float*)d_in[7];
    float* y = (float*)d_out;

    float* C   = (float*)d_ws;                    // 4 MFMA maps, 1.6 MB
    float* rsm = C + C4ELEMS;                     // [b][i][NT]
    float* rsr = rsm + (size_t)NB * 2 * NT;       // [b][j][RSRLEN], 99 leading zeros

    corr_kernel<<<dim3(NB * 2 * NTT), dim3(256), 0, stream>>>(x_mic, x_ref, C, rsm, rsr);
    csy_kernel<<<dim3(NB * NT), dim3(256), 0, stream>>>(
        C, rsm, rsr, w_conv, b_conv, w_mic, b_mic, w_ref, b_ref, x_ref, y);
}